// Round 1
// baseline (11182.475 us; speedup 1.0000x reference)
//
#include <hip/hip_runtime.h>

#define NN 100000
#define NE 3200000
#define NG 128
#define HID 64

// ---------------- gcn_norm ----------------
__global__ __launch_bounds__(256) void deg_kernel(const int* __restrict__ dst,
                                                  int* __restrict__ deg, int E) {
    int e = blockIdx.x * 256 + threadIdx.x;
    if (e < E) atomicAdd(&deg[dst[e]], 1);
}

__global__ __launch_bounds__(256) void dis_kernel(const int* __restrict__ deg,
                                                  float* __restrict__ dis, int N) {
    int i = blockIdx.x * 256 + threadIdx.x;
    if (i < N) dis[i] = rsqrtf((float)deg[i] + 1.0f);  // +1 = self loop
}

__global__ __launch_bounds__(256) void norm_kernel(const int* __restrict__ src,
                                                   const int* __restrict__ dst,
                                                   const float* __restrict__ dis,
                                                   float* __restrict__ norm, int E) {
    int e = blockIdx.x * 256 + threadIdx.x;
    if (e < E) norm[e] = dis[src[e]] * dis[dst[e]];
}

// ---------------- per-layer GEMM (+fused prev bias/relu, +self-loop agg init) ----
// in:[N,K] (optionally pre-activation: apply +bias,relu while loading)
// w:[K,64] row-major. t[i,:] = act(in[i,:]) @ w ; agg[i,:] = t[i,:] * dis[i]^2
// NOTE: `in` may alias `agg` (in-place). Safe: block reads its 64 rows into LDS
// before writing those same rows; blocks own disjoint rows.
template <int K, bool BIASRELU>
__global__ __launch_bounds__(256) void gemm_kernel(const float* in,
                                                   const float* __restrict__ w,
                                                   const float* __restrict__ bias,
                                                   const float* __restrict__ dis,
                                                   float* __restrict__ t,
                                                   float* agg, int N) {
    constexpr int KP = K + 1;
    __shared__ float w_s[K * 64];
    __shared__ float in_s[64 * KP];
    const int tid  = threadIdx.x;
    const int row0 = blockIdx.x * 64;
    const int rows = min(64, N - row0);

    for (int i = tid; i < K * 64; i += 256) w_s[i] = w[i];
    for (int i = tid; i < rows * K; i += 256) {
        int r = i / K, k = i - r * K;
        float v = in[(size_t)(row0 + r) * K + k];
        if (BIASRELU) v = fmaxf(v + bias[k], 0.0f);
        in_s[r * KP + k] = v;
    }
    __syncthreads();

    const int r  = tid & 63;   // lane = row  -> w_s reads are wave-broadcast
    const int cg = tid >> 6;   // wave = 16-col group
    float acc[16];
#pragma unroll
    for (int i = 0; i < 16; ++i) acc[i] = 0.0f;
#pragma unroll
    for (int k = 0; k < K; ++k) {
        float a = in_s[r * KP + k];
#pragma unroll
        for (int cc = 0; cc < 16; ++cc)
            acc[cc] += a * w_s[k * 64 + cg * 16 + cc];
    }
    const int row = row0 + r;
    if (row < N) {
        float sn = dis[row];
        sn = sn * sn;  // self-loop norm = 1/deg
        float* tp = t   + (size_t)row * HID + cg * 16;
        float* ap = agg + (size_t)row * HID + cg * 16;
#pragma unroll
        for (int v4 = 0; v4 < 4; ++v4) {
            float4 tv = make_float4(acc[4 * v4], acc[4 * v4 + 1],
                                    acc[4 * v4 + 2], acc[4 * v4 + 3]);
            reinterpret_cast<float4*>(tp)[v4] = tv;
            float4 av = make_float4(tv.x * sn, tv.y * sn, tv.z * sn, tv.w * sn);
            reinterpret_cast<float4*>(ap)[v4] = av;
        }
    }
}

// ---------------- edge scatter: agg[dst] += t[src]*norm --------------------
__global__ __launch_bounds__(256) void scatter_kernel(const float* __restrict__ t,
                                                      const float* __restrict__ norm,
                                                      const int* __restrict__ src,
                                                      const int* __restrict__ dst,
                                                      float* __restrict__ agg, int E) {
    long long tid = (long long)blockIdx.x * 256 + threadIdx.x;
    int e = (int)(tid >> 4);
    if (e >= E) return;
    int q = (int)(tid & 15);
    int s = src[e], d = dst[e];
    float nm = norm[e];
    float4 v = reinterpret_cast<const float4*>(t + (size_t)s * HID)[q];
    float* out = agg + (size_t)d * HID + q * 4;
    atomicAdd(out + 0, v.x * nm);
    atomicAdd(out + 1, v.y * nm);
    atomicAdd(out + 2, v.z * nm);
    atomicAdd(out + 3, v.w * nm);
}

// ---------------- mean pool (batch is sorted) ------------------------------
__global__ __launch_bounds__(256) void pool_kernel(const float* __restrict__ agg,
                                                   const float* __restrict__ b4,
                                                   const int* __restrict__ batch,
                                                   float* __restrict__ sums,
                                                   float* __restrict__ cnts, int N) {
    __shared__ float lsum[NG * HID];  // 32 KB (worst-case span = all graphs)
    __shared__ float lcnt[NG];
    const int tid  = threadIdx.x;
    const int base = blockIdx.x * 256;
    const int last = min(base + 256, N) - 1;
    const int gfirst = batch[base];
    const int glast  = batch[last];
    const int span   = glast - gfirst + 1;

    for (int i = tid; i < span * HID; i += 256) lsum[i] = 0.0f;
    for (int i = tid; i < span; i += 256) lcnt[i] = 0.0f;
    __syncthreads();

    const int f = tid & 63, sub = tid >> 6;
    for (int n = base + sub; n < min(base + 256, N); n += 4) {
        int g = batch[n];
        float v = fmaxf(agg[(size_t)n * HID + f] + b4[f], 0.0f);
        atomicAdd(&lsum[(g - gfirst) * HID + f], v);
        if (f == 0) atomicAdd(&lcnt[g - gfirst], 1.0f);
    }
    __syncthreads();

    for (int i = tid; i < span * HID; i += 256)
        atomicAdd(&sums[(size_t)gfirst * HID + i], lsum[i]);
    for (int i = tid; i < span; i += 256) atomicAdd(&cnts[gfirst + i], lcnt[i]);
}

__global__ __launch_bounds__(256) void finalize_kernel(const float* __restrict__ sums,
                                                       const float* __restrict__ cnts,
                                                       float* __restrict__ out) {
    int i = blockIdx.x * 256 + threadIdx.x;
    if (i < NG * HID) out[i] = sums[i] / fmaxf(cnts[i >> 6], 1.0f);
}

// ---------------- launch ----------------
extern "C" void kernel_launch(void* const* d_in, const int* in_sizes, int n_in,
                              void* d_out, int out_size, void* d_ws, size_t ws_size,
                              hipStream_t stream) {
    const float* x  = (const float*)d_in[0];
    const float* w1 = (const float*)d_in[1];
    const float* b1 = (const float*)d_in[2];
    const float* w2 = (const float*)d_in[3];
    const float* b2 = (const float*)d_in[4];
    const float* w3 = (const float*)d_in[5];
    const float* b3 = (const float*)d_in[6];
    const float* w4 = (const float*)d_in[7];
    const float* b4 = (const float*)d_in[8];
    const int* ei    = (const int*)d_in[9];
    const int* batch = (const int*)d_in[10];
    const int* src = ei;
    const int* dst = ei + NE;

    // workspace layout (floats)
    float* T    = (float*)d_ws;                 // 6.4M
    float* AGG  = T + (size_t)NN * HID;         // 6.4M
    float* norm = AGG + (size_t)NN * HID;       // 3.2M
    float* dis  = norm + NE;                    // 100K
    int*   deg  = (int*)(dis + NN);             // 100K
    float* sums = (float*)(deg + NN);           // 8192
    float* cnts = sums + NG * HID;              // 128

    float* out = (float*)d_out;

    const int EB = (NE + 255) / 256;       // edge-grid
    const int NB = (NN + 255) / 256;       // node-grid
    const int GB = (NN + 63) / 64;         // gemm row-tiles
    const long long st = (long long)NE * 16;
    const int SB = (int)((st + 255) / 256);  // scatter grid

    hipMemsetAsync(deg, 0, NN * sizeof(int), stream);
    hipMemsetAsync(sums, 0, (NG * HID + NG) * sizeof(float), stream);

    deg_kernel<<<EB, 256, 0, stream>>>(dst, deg, NE);
    dis_kernel<<<NB, 256, 0, stream>>>(deg, dis, NN);
    norm_kernel<<<EB, 256, 0, stream>>>(src, dst, dis, norm, NE);

    // layer 1 (K=15, no fused pre-activation)
    gemm_kernel<15, false><<<GB, 256, 0, stream>>>(x, w1, nullptr, dis, T, AGG, NN);
    scatter_kernel<<<SB, 256, 0, stream>>>(T, norm, src, dst, AGG, NE);
    // layer 2..4: fuse prev layer's bias+relu into GEMM load
    gemm_kernel<64, true><<<GB, 256, 0, stream>>>(AGG, w2, b1, dis, T, AGG, NN);
    scatter_kernel<<<SB, 256, 0, stream>>>(T, norm, src, dst, AGG, NE);
    gemm_kernel<64, true><<<GB, 256, 0, stream>>>(AGG, w3, b2, dis, T, AGG, NN);
    scatter_kernel<<<SB, 256, 0, stream>>>(T, norm, src, dst, AGG, NE);
    gemm_kernel<64, true><<<GB, 256, 0, stream>>>(AGG, w4, b3, dis, T, AGG, NN);
    scatter_kernel<<<SB, 256, 0, stream>>>(T, norm, src, dst, AGG, NE);

    pool_kernel<<<NB, 256, 0, stream>>>(AGG, b4, batch, sums, cnts, NN);
    finalize_kernel<<<(NG * HID + 255) / 256, 256, 0, stream>>>(sums, cnts, out);
}

// Round 2
// 1068.768 us; speedup vs baseline: 10.4630x; 10.4630x over previous
//
#include <hip/hip_runtime.h>

#define NN 100000
#define NE 3200000
#define NG 128
#define HID 64

// ---------------- degree + dis ----------------
__global__ __launch_bounds__(256) void deg_kernel(const int* __restrict__ dst,
                                                  int* __restrict__ deg, int E) {
    int e = blockIdx.x * 256 + threadIdx.x;
    if (e < E) atomicAdd(&deg[dst[e]], 1);
}

__global__ __launch_bounds__(256) void dis_kernel(const int* __restrict__ deg,
                                                  float* __restrict__ dis, int N) {
    int i = blockIdx.x * 256 + threadIdx.x;
    if (i < N) dis[i] = rsqrtf((float)deg[i] + 1.0f);  // +1 = self loop
}

// ---------------- exclusive scan of deg -> rowptr (3-kernel) ----------------
__global__ __launch_bounds__(256) void scan1_kernel(const int* __restrict__ deg,
                                                    int* __restrict__ bsum, int N) {
    __shared__ int s[256];
    int i = blockIdx.x * 256 + threadIdx.x;
    s[threadIdx.x] = (i < N) ? deg[i] : 0;
    __syncthreads();
    for (int off = 128; off > 0; off >>= 1) {
        if (threadIdx.x < off) s[threadIdx.x] += s[threadIdx.x + off];
        __syncthreads();
    }
    if (threadIdx.x == 0) bsum[blockIdx.x] = s[0];
}

__global__ __launch_bounds__(512) void scan2_kernel(int* __restrict__ bsum, int nb) {
    __shared__ int s[512];
    int v = (threadIdx.x < (unsigned)nb) ? bsum[threadIdx.x] : 0;
    s[threadIdx.x] = v;
    __syncthreads();
    for (int off = 1; off < 512; off <<= 1) {
        int t = (threadIdx.x >= off) ? s[threadIdx.x - off] : 0;
        __syncthreads();
        s[threadIdx.x] += t;
        __syncthreads();
    }
    if (threadIdx.x < (unsigned)nb) bsum[threadIdx.x] = s[threadIdx.x] - v;  // exclusive
}

__global__ __launch_bounds__(256) void scan3_kernel(const int* __restrict__ deg,
                                                    const int* __restrict__ bsum,
                                                    int* __restrict__ rowptr,
                                                    int* __restrict__ cursor, int N) {
    __shared__ int s[256];
    int i = blockIdx.x * 256 + threadIdx.x;
    int v = (i < N) ? deg[i] : 0;
    s[threadIdx.x] = v;
    __syncthreads();
    for (int off = 1; off < 256; off <<= 1) {
        int t = (threadIdx.x >= off) ? s[threadIdx.x - off] : 0;
        __syncthreads();
        s[threadIdx.x] += t;
        __syncthreads();
    }
    int incl = s[threadIdx.x] + bsum[blockIdx.x];
    if (i < N) {
        int ex = incl - v;
        rowptr[i] = ex;
        cursor[i] = ex;
        if (i == N - 1) rowptr[N] = incl;
    }
}

// ---------------- CSR fill (order within a row is irrelevant for a sum) -----
__global__ __launch_bounds__(256) void fill_kernel(const int* __restrict__ src,
                                                   const int* __restrict__ dst,
                                                   int* __restrict__ cursor,
                                                   int* __restrict__ csr_src, int E) {
    int e = blockIdx.x * 256 + threadIdx.x;
    if (e < E) {
        int p = atomicAdd(&cursor[dst[e]], 1);
        csr_src[p] = src[e];
    }
}

// ---------------- per-layer GEMM: t[i,:] = act(in[i,:]) @ w * dis[i] --------
// NOTE: `in` may alias other buffers only across kernels, never within.
template <int K, bool BIASRELU>
__global__ __launch_bounds__(256) void gemm_kernel(const float* __restrict__ in,
                                                   const float* __restrict__ w,
                                                   const float* __restrict__ bias,
                                                   const float* __restrict__ dis,
                                                   float* __restrict__ t, int N) {
    constexpr int KP = K + 1;
    __shared__ float w_s[K * 64];
    __shared__ float in_s[64 * KP];
    const int tid  = threadIdx.x;
    const int row0 = blockIdx.x * 64;
    const int rows = min(64, N - row0);

    for (int i = tid; i < K * 64; i += 256) w_s[i] = w[i];
    for (int i = tid; i < rows * K; i += 256) {
        int r = i / K, k = i - r * K;
        float v = in[(size_t)(row0 + r) * K + k];
        if (BIASRELU) v = fmaxf(v + bias[k], 0.0f);
        in_s[r * KP + k] = v;
    }
    __syncthreads();

    const int r  = tid & 63;   // lane = row -> w_s reads wave-broadcast
    const int cg = tid >> 6;   // wave = 16-col group
    float acc[16];
#pragma unroll
    for (int i = 0; i < 16; ++i) acc[i] = 0.0f;
#pragma unroll
    for (int k = 0; k < K; ++k) {
        float a = in_s[r * KP + k];
#pragma unroll
        for (int cc = 0; cc < 16; ++cc)
            acc[cc] += a * w_s[k * 64 + cg * 16 + cc];
    }
    const int row = row0 + r;
    if (row < N) {
        float sd = dis[row];
        float* tp = t + (size_t)row * HID + cg * 16;
#pragma unroll
        for (int v4 = 0; v4 < 4; ++v4) {
            reinterpret_cast<float4*>(tp)[v4] =
                make_float4(acc[4 * v4] * sd, acc[4 * v4 + 1] * sd,
                            acc[4 * v4 + 2] * sd, acc[4 * v4 + 3] * sd);
        }
    }
}

// ---------------- gather: agg[d,:] = dis[d] * (t[d,:] + sum t[src,:]) -------
// one wave per dst node; lane = feature column
__global__ __launch_bounds__(256) void gather_kernel(const float* __restrict__ t,
                                                     const int* __restrict__ csr_src,
                                                     const int* __restrict__ rowptr,
                                                     const float* __restrict__ dis,
                                                     float* __restrict__ agg, int N) {
    const int w    = (blockIdx.x * 256 + threadIdx.x) >> 6;
    const int lane = threadIdx.x & 63;
    if (w >= N) return;
    const int start = rowptr[w];
    const int end   = rowptr[w + 1];
    const float* tl = t + lane;

    float acc = 0.0f;
    for (int j0 = start; j0 < end; j0 += 64) {
        int j   = j0 + lane;
        int s   = (j < end) ? csr_src[j] : 0;
        int cnt = min(64, end - j0);
        int k = 0;
        for (; k + 4 <= cnt; k += 4) {
            int s0 = __shfl(s, k);
            int s1 = __shfl(s, k + 1);
            int s2 = __shfl(s, k + 2);
            int s3 = __shfl(s, k + 3);
            float v0 = tl[s0 * HID];
            float v1 = tl[s1 * HID];
            float v2 = tl[s2 * HID];
            float v3 = tl[s3 * HID];
            acc += v0; acc += v1; acc += v2; acc += v3;
        }
        for (; k < cnt; ++k) {
            int ss = __shfl(s, k);
            acc += tl[ss * HID];
        }
    }
    float sn = dis[w];
    agg[(size_t)w * HID + lane] = sn * (acc + tl[w * HID]);
}

// ---------------- mean pool (batch is sorted) ------------------------------
__global__ __launch_bounds__(256) void pool_kernel(const float* __restrict__ agg,
                                                   const float* __restrict__ b4,
                                                   const int* __restrict__ batch,
                                                   float* __restrict__ sums,
                                                   float* __restrict__ cnts, int N) {
    __shared__ float lsum[NG * HID];
    __shared__ float lcnt[NG];
    const int tid  = threadIdx.x;
    const int base = blockIdx.x * 256;
    const int last = min(base + 256, N) - 1;
    const int gfirst = batch[base];
    const int glast  = batch[last];
    const int span   = glast - gfirst + 1;

    for (int i = tid; i < span * HID; i += 256) lsum[i] = 0.0f;
    for (int i = tid; i < span; i += 256) lcnt[i] = 0.0f;
    __syncthreads();

    const int f = tid & 63, sub = tid >> 6;
    for (int n = base + sub; n < min(base + 256, N); n += 4) {
        int g = batch[n];
        float v = fmaxf(agg[(size_t)n * HID + f] + b4[f], 0.0f);
        atomicAdd(&lsum[(g - gfirst) * HID + f], v);
        if (f == 0) atomicAdd(&lcnt[g - gfirst], 1.0f);
    }
    __syncthreads();

    for (int i = tid; i < span * HID; i += 256)
        atomicAdd(&sums[(size_t)gfirst * HID + i], lsum[i]);
    for (int i = tid; i < span; i += 256) atomicAdd(&cnts[gfirst + i], lcnt[i]);
}

__global__ __launch_bounds__(256) void finalize_kernel(const float* __restrict__ sums,
                                                       const float* __restrict__ cnts,
                                                       float* __restrict__ out) {
    int i = blockIdx.x * 256 + threadIdx.x;
    if (i < NG * HID) out[i] = sums[i] / fmaxf(cnts[i >> 6], 1.0f);
}

// ---------------- launch ----------------
extern "C" void kernel_launch(void* const* d_in, const int* in_sizes, int n_in,
                              void* d_out, int out_size, void* d_ws, size_t ws_size,
                              hipStream_t stream) {
    const float* x  = (const float*)d_in[0];
    const float* w1 = (const float*)d_in[1];
    const float* b1 = (const float*)d_in[2];
    const float* w2 = (const float*)d_in[3];
    const float* b2 = (const float*)d_in[4];
    const float* w3 = (const float*)d_in[5];
    const float* b3 = (const float*)d_in[6];
    const float* w4 = (const float*)d_in[7];
    const float* b4 = (const float*)d_in[8];
    const int* ei    = (const int*)d_in[9];
    const int* batch = (const int*)d_in[10];
    const int* src = ei;
    const int* dst = ei + NE;

    // workspace layout
    float* T       = (float*)d_ws;               // NN*64
    float* AGG     = T + (size_t)NN * HID;       // NN*64
    int*   csr_src = (int*)(AGG + (size_t)NN * HID);  // NE
    int*   rowptr  = csr_src + NE;               // NN+1
    int*   cursor  = rowptr + NN + 1;            // NN
    float* dis     = (float*)(cursor + NN);      // NN
    int*   deg     = (int*)(dis + NN);           // NN
    int*   bsum    = deg + NN;                   // 512
    float* sums    = (float*)(bsum + 512);       // NG*HID
    float* cnts    = sums + NG * HID;            // NG

    float* out = (float*)d_out;

    const int EB = (NE + 255) / 256;
    const int NB = (NN + 255) / 256;       // 391
    const int GB = (NN + 63) / 64;
    const int WB = (NN * 64 + 255) / 256;  // gather: 1 wave/node, 4 nodes/block

    hipMemsetAsync(deg, 0, NN * sizeof(int), stream);
    hipMemsetAsync(sums, 0, (NG * HID + NG) * sizeof(float), stream);

    deg_kernel<<<EB, 256, 0, stream>>>(dst, deg, NE);
    dis_kernel<<<NB, 256, 0, stream>>>(deg, dis, NN);
    scan1_kernel<<<NB, 256, 0, stream>>>(deg, bsum, NN);
    scan2_kernel<<<1, 512, 0, stream>>>(bsum, NB);
    scan3_kernel<<<NB, 256, 0, stream>>>(deg, bsum, rowptr, cursor, NN);
    fill_kernel<<<EB, 256, 0, stream>>>(src, dst, cursor, csr_src, NE);

    gemm_kernel<15, false><<<GB, 256, 0, stream>>>(x, w1, nullptr, dis, T, NN);
    gather_kernel<<<WB, 256, 0, stream>>>(T, csr_src, rowptr, dis, AGG, NN);
    gemm_kernel<64, true><<<GB, 256, 0, stream>>>(AGG, w2, b1, dis, T, NN);
    gather_kernel<<<WB, 256, 0, stream>>>(T, csr_src, rowptr, dis, AGG, NN);
    gemm_kernel<64, true><<<GB, 256, 0, stream>>>(AGG, w3, b2, dis, T, NN);
    gather_kernel<<<WB, 256, 0, stream>>>(T, csr_src, rowptr, dis, AGG, NN);
    gemm_kernel<64, true><<<GB, 256, 0, stream>>>(AGG, w4, b3, dis, T, NN);
    gather_kernel<<<WB, 256, 0, stream>>>(T, csr_src, rowptr, dis, AGG, NN);

    pool_kernel<<<NB, 256, 0, stream>>>(AGG, b4, batch, sums, cnts, NN);
    finalize_kernel<<<(NG * HID + 255) / 256, 256, 0, stream>>>(sums, cnts, out);
}

// Round 4
// 798.996 us; speedup vs baseline: 13.9957x; 1.3376x over previous
//
#include <hip/hip_runtime.h>

#define NN 100000
#define NE 3200000
#define NG 128
#define HID 64

#define BSH 9                       // nodes per bucket = 512
#define BNODES 512
#define NBK ((NN + BNODES - 1) / BNODES)   // 196
#define CCH 4096                    // edges staged per block in bscatter

// ---------------- bucket count: hist of dst>>BSH ----------------
__global__ __launch_bounds__(256) void bcount_kernel(const int* __restrict__ dst,
                                                     int* __restrict__ bcnt, int E) {
    __shared__ int h[NBK];
    for (int i = threadIdx.x; i < NBK; i += 256) h[i] = 0;
    __syncthreads();
    for (int e = blockIdx.x * 256 + threadIdx.x; e < E; e += gridDim.x * 256)
        atomicAdd(&h[dst[e] >> BSH], 1);
    __syncthreads();
    for (int i = threadIdx.x; i < NBK; i += 256)
        if (h[i]) atomicAdd(&bcnt[i], h[i]);
}

// ---------------- bucket scan (196 values, 1 block) ----------------
__global__ __launch_bounds__(256) void bscan_kernel(const int* __restrict__ bcnt,
                                                    int* __restrict__ bbase,
                                                    int* __restrict__ bcur, int E) {
    __shared__ int s[NBK];
    int t = threadIdx.x;
    if (t < NBK) s[t] = bcnt[t];
    __syncthreads();
    if (t == 0) {
        int acc = 0;
        for (int i = 0; i < NBK; ++i) { int v = s[i]; s[i] = acc; acc += v; }
    }
    __syncthreads();
    if (t < NBK) { bbase[t] = s[t]; bcur[t] = s[t]; }
    if (t == 0) bbase[NBK] = E;
}

// ---------------- scatter (src,dst) pairs into bucket-sorted order ----------
__global__ __launch_bounds__(256) void bscatter_kernel(const int* __restrict__ src,
                                                       const int* __restrict__ dst,
                                                       int* __restrict__ bcur,
                                                       int2* __restrict__ pairs, int E) {
    __shared__ int2 stage[CCH];     // 32 KB
    __shared__ int cnt[NBK];
    __shared__ int base[NBK];
    const int e0 = blockIdx.x * CCH;
    const int n  = min(CCH, E - e0);
    if (n <= 0) return;
    for (int i = threadIdx.x; i < NBK; i += 256) cnt[i] = 0;
    __syncthreads();
    for (int i = threadIdx.x; i < n; i += 256) {
        int2 p = make_int2(src[e0 + i], dst[e0 + i]);
        stage[i] = p;
        atomicAdd(&cnt[p.y >> BSH], 1);
    }
    __syncthreads();
    for (int i = threadIdx.x; i < NBK; i += 256) {
        int c = cnt[i];
        base[i] = c ? atomicAdd(&bcur[i], c) : 0;
        cnt[i] = 0;                 // reuse as local cursor
    }
    __syncthreads();
    for (int i = threadIdx.x; i < n; i += 256) {
        int2 p = stage[i];
        int b = p.y >> BSH;
        int pos = base[b] + atomicAdd(&cnt[b], 1);
        pairs[pos] = p;
    }
}

// ---------------- per-bucket CSR build: rowptr, dis, csr_src ----------------
// one block per bucket; CSR write window ~65 KB -> L2-resident, no write amp
__global__ __launch_bounds__(256) void csr_kernel(const int2* __restrict__ pairs,
                                                  const int* __restrict__ bbase,
                                                  int* __restrict__ rowptr,
                                                  int* __restrict__ csr_src,
                                                  float* __restrict__ dis,
                                                  int N, int E) {
    __shared__ int hist[BNODES];
    __shared__ int cur[BNODES];
    __shared__ int s[256];
    const int b     = blockIdx.x;
    const int t     = threadIdx.x;
    const int node0 = b << BSH;
    const int nn    = min(BNODES, N - node0);
    const int p0 = bbase[b], p1 = bbase[b + 1];

    for (int i = t; i < BNODES; i += 256) hist[i] = 0;
    __syncthreads();
    for (int i = p0 + t; i < p1; i += 256)
        atomicAdd(&hist[pairs[i].y - node0], 1);
    __syncthreads();

    // exclusive scan of hist[0..BNODES) : pair-sum per thread, Hillis-Steele 256
    int h0 = hist[2 * t], h1 = hist[2 * t + 1];
    int v = h0 + h1;
    s[t] = v;
    __syncthreads();
    for (int off = 1; off < 256; off <<= 1) {
        int u = (t >= off) ? s[t - off] : 0;
        __syncthreads();
        s[t] += u;
        __syncthreads();
    }
    int excl = s[t] - v;            // exclusive prefix of pair t
    int e0 = p0 + excl;             // row start of node 2t
    int e1 = e0 + h0;               // row start of node 2t+1
    if (2 * t < nn) {
        rowptr[node0 + 2 * t] = e0;
        dis[node0 + 2 * t] = rsqrtf((float)h0 + 1.0f);
        cur[2 * t] = e0;
    }
    if (2 * t + 1 < nn) {
        rowptr[node0 + 2 * t + 1] = e1;
        dis[node0 + 2 * t + 1] = rsqrtf((float)h1 + 1.0f);
        cur[2 * t + 1] = e1;
    }
    if (b == NBK - 1 && t == 0) rowptr[N] = E;
    __syncthreads();

    for (int i = p0 + t; i < p1; i += 256) {
        int2 p = pairs[i];
        int pos = atomicAdd(&cur[p.y - node0], 1);
        csr_src[pos] = p.x;
    }
}

// ---------------- per-layer GEMM: t[i,:] = act(in[i,:]) @ w * dis[i] --------
template <int K, bool BIASRELU>
__global__ __launch_bounds__(256) void gemm_kernel(const float* __restrict__ in,
                                                   const float* __restrict__ w,
                                                   const float* __restrict__ bias,
                                                   const float* __restrict__ dis,
                                                   float* __restrict__ t, int N) {
    constexpr int KP = K + 1;
    __shared__ float w_s[K * 64];
    __shared__ float in_s[64 * KP];
    const int tid  = threadIdx.x;
    const int row0 = blockIdx.x * 64;
    const int rows = min(64, N - row0);

    for (int i = tid; i < K * 64; i += 256) w_s[i] = w[i];
    for (int i = tid; i < rows * K; i += 256) {
        int r = i / K, k = i - r * K;
        float v = in[(size_t)(row0 + r) * K + k];
        if (BIASRELU) v = fmaxf(v + bias[k], 0.0f);
        in_s[r * KP + k] = v;
    }
    __syncthreads();

    const int r  = tid & 63;
    const int cg = tid >> 6;
    float acc[16];
#pragma unroll
    for (int i = 0; i < 16; ++i) acc[i] = 0.0f;
#pragma unroll
    for (int k = 0; k < K; ++k) {
        float a = in_s[r * KP + k];
#pragma unroll
        for (int cc = 0; cc < 16; ++cc)
            acc[cc] += a * w_s[k * 64 + cg * 16 + cc];
    }
    const int row = row0 + r;
    if (row < N) {
        float sd = dis[row];
        float* tp = t + (size_t)row * HID + cg * 16;
#pragma unroll
        for (int v4 = 0; v4 < 4; ++v4) {
            reinterpret_cast<float4*>(tp)[v4] =
                make_float4(acc[4 * v4] * sd, acc[4 * v4 + 1] * sd,
                            acc[4 * v4 + 2] * sd, acc[4 * v4 + 3] * sd);
        }
    }
}

// ---------------- gather: agg[d,:] = dis[d] * (t[d,:] + sum t[src,:]) -------
__global__ __launch_bounds__(256) void gather_kernel(const float* __restrict__ t,
                                                     const int* __restrict__ csr_src,
                                                     const int* __restrict__ rowptr,
                                                     const float* __restrict__ dis,
                                                     float* __restrict__ agg, int N) {
    const int w    = (blockIdx.x * 256 + threadIdx.x) >> 6;
    const int lane = threadIdx.x & 63;
    if (w >= N) return;
    const int start = rowptr[w];
    const int end   = rowptr[w + 1];
    const float* tl = t + lane;

    float acc = 0.0f;
    for (int j0 = start; j0 < end; j0 += 64) {
        int j   = j0 + lane;
        int s   = (j < end) ? csr_src[j] : 0;
        int cnt = min(64, end - j0);
        int k = 0;
        for (; k + 4 <= cnt; k += 4) {
            int s0 = __shfl(s, k);
            int s1 = __shfl(s, k + 1);
            int s2 = __shfl(s, k + 2);
            int s3 = __shfl(s, k + 3);
            float v0 = tl[s0 * HID];
            float v1 = tl[s1 * HID];
            float v2 = tl[s2 * HID];
            float v3 = tl[s3 * HID];
            acc += v0; acc += v1; acc += v2; acc += v3;
        }
        for (; k < cnt; ++k) {
            int ss = __shfl(s, k);
            acc += tl[ss * HID];
        }
    }
    float sn = dis[w];
    agg[(size_t)w * HID + lane] = sn * (acc + tl[w * HID]);
}

// ---------------- mean pool (batch is sorted) ------------------------------
__global__ __launch_bounds__(256) void pool_kernel(const float* __restrict__ agg,
                                                   const float* __restrict__ b4,
                                                   const int* __restrict__ batch,
                                                   float* __restrict__ sums,
                                                   float* __restrict__ cnts, int N) {
    __shared__ float lsum[NG * HID];
    __shared__ float lcnt[NG];
    const int tid  = threadIdx.x;
    const int base = blockIdx.x * 256;
    const int last = min(base + 256, N) - 1;
    const int gfirst = batch[base];
    const int glast  = batch[last];
    const int span   = glast - gfirst + 1;

    for (int i = tid; i < span * HID; i += 256) lsum[i] = 0.0f;
    for (int i = tid; i < span; i += 256) lcnt[i] = 0.0f;
    __syncthreads();

    const int f = tid & 63, sub = tid >> 6;
    for (int n = base + sub; n < min(base + 256, N); n += 4) {
        int g = batch[n];
        float v = fmaxf(agg[(size_t)n * HID + f] + b4[f], 0.0f);
        atomicAdd(&lsum[(g - gfirst) * HID + f], v);
        if (f == 0) atomicAdd(&lcnt[g - gfirst], 1.0f);
    }
    __syncthreads();

    for (int i = tid; i < span * HID; i += 256)
        atomicAdd(&sums[(size_t)gfirst * HID + i], lsum[i]);
    for (int i = tid; i < span; i += 256) atomicAdd(&cnts[gfirst + i], lcnt[i]);
}

__global__ __launch_bounds__(256) void finalize_kernel(const float* __restrict__ sums,
                                                       const float* __restrict__ cnts,
                                                       float* __restrict__ out) {
    int i = blockIdx.x * 256 + threadIdx.x;
    if (i < NG * HID) out[i] = sums[i] / fmaxf(cnts[i >> 6], 1.0f);
}

// ---------------- launch ----------------
extern "C" void kernel_launch(void* const* d_in, const int* in_sizes, int n_in,
                              void* d_out, int out_size, void* d_ws, size_t ws_size,
                              hipStream_t stream) {
    const float* x  = (const float*)d_in[0];
    const float* w1 = (const float*)d_in[1];
    const float* b1 = (const float*)d_in[2];
    const float* w2 = (const float*)d_in[3];
    const float* b2 = (const float*)d_in[4];
    const float* w3 = (const float*)d_in[5];
    const float* b3 = (const float*)d_in[6];
    const float* w4 = (const float*)d_in[7];
    const float* b4 = (const float*)d_in[8];
    const int* ei    = (const int*)d_in[9];
    const int* batch = (const int*)d_in[10];
    const int* src = ei;
    const int* dst = ei + NE;

    // workspace layout (pairs aliases T: pairs dead before first gemm writes T)
    float* T       = (float*)d_ws;                    // NN*HID floats == NE int2
    int2*  pairs   = (int2*)d_ws;
    float* AGG     = T + (size_t)NN * HID;            // NN*HID
    int*   csr_src = (int*)(AGG + (size_t)NN * HID);  // NE
    int*   rowptr  = csr_src + NE;                    // NN+1
    float* dis     = (float*)(rowptr + NN + 1);       // NN
    int*   bcnt    = (int*)(dis + NN);                // NBK
    int*   bbase   = bcnt + NBK;                      // NBK+1
    int*   bcur    = bbase + NBK + 1;                 // NBK
    float* sums    = (float*)(bcur + NBK);            // NG*HID
    float* cnts    = sums + NG * HID;                 // NG

    float* out = (float*)d_out;

    const int NB = (NN + 255) / 256;
    const int GB = (NN + 63) / 64;
    const int WB = (NN * 64 + 255) / 256;
    const int CB = (NE + CCH - 1) / CCH;

    hipMemsetAsync(bcnt, 0, NBK * sizeof(int), stream);
    hipMemsetAsync(sums, 0, (NG * HID + NG) * sizeof(float), stream);

    bcount_kernel<<<512, 256, 0, stream>>>(dst, bcnt, NE);
    bscan_kernel<<<1, 256, 0, stream>>>(bcnt, bbase, bcur, NE);
    bscatter_kernel<<<CB, 256, 0, stream>>>(src, dst, bcur, pairs, NE);
    csr_kernel<<<NBK, 256, 0, stream>>>(pairs, bbase, rowptr, csr_src, dis, NN, NE);

    gemm_kernel<15, false><<<GB, 256, 0, stream>>>(x, w1, nullptr, dis, T, NN);
    gather_kernel<<<WB, 256, 0, stream>>>(T, csr_src, rowptr, dis, AGG, NN);
    gemm_kernel<64, true><<<GB, 256, 0, stream>>>(AGG, w2, b1, dis, T, NN);
    gather_kernel<<<WB, 256, 0, stream>>>(T, csr_src, rowptr, dis, AGG, NN);
    gemm_kernel<64, true><<<GB, 256, 0, stream>>>(AGG, w3, b2, dis, T, NN);
    gather_kernel<<<WB, 256, 0, stream>>>(T, csr_src, rowptr, dis, AGG, NN);
    gemm_kernel<64, true><<<GB, 256, 0, stream>>>(AGG, w4, b3, dis, T, NN);
    gather_kernel<<<WB, 256, 0, stream>>>(T, csr_src, rowptr, dis, AGG, NN);

    pool_kernel<<<NB, 256, 0, stream>>>(AGG, b4, batch, sums, cnts, NN);
    finalize_kernel<<<(NG * HID + 255) / 256, 256, 0, stream>>>(sums, cnts, out);
}

// Round 7
// 569.742 us; speedup vs baseline: 19.6273x; 1.4024x over previous
//
#include <hip/hip_runtime.h>
#include <hip/hip_fp16.h>

#define NN 100000
#define NE 3200000
#define NG 128
#define HID 64

#define BSH 9                       // nodes per bucket = 512
#define BNODES 512
#define NBK ((NN + BNODES - 1) / BNODES)   // 196
#define CCH 4096                    // edges staged per block in bscatter

// ---------------- bucket count: hist of dst>>BSH ----------------
__global__ __launch_bounds__(256) void bcount_kernel(const int* __restrict__ dst,
                                                     int* __restrict__ bcnt, int E) {
    __shared__ int h[NBK];
    for (int i = threadIdx.x; i < NBK; i += 256) h[i] = 0;
    __syncthreads();
    for (int e = blockIdx.x * 256 + threadIdx.x; e < E; e += gridDim.x * 256)
        atomicAdd(&h[dst[e] >> BSH], 1);
    __syncthreads();
    for (int i = threadIdx.x; i < NBK; i += 256)
        if (h[i]) atomicAdd(&bcnt[i], h[i]);
}

// ---------------- bucket scan (196 values, 1 block) ----------------
__global__ __launch_bounds__(256) void bscan_kernel(const int* __restrict__ bcnt,
                                                    int* __restrict__ bbase,
                                                    int* __restrict__ bcur, int E) {
    __shared__ int s[NBK];
    int t = threadIdx.x;
    if (t < NBK) s[t] = bcnt[t];
    __syncthreads();
    if (t == 0) {
        int acc = 0;
        for (int i = 0; i < NBK; ++i) { int v = s[i]; s[i] = acc; acc += v; }
    }
    __syncthreads();
    if (t < NBK) { bbase[t] = s[t]; bcur[t] = s[t]; }
    if (t == 0) bbase[NBK] = E;
}

// ---------------- scatter (src,dst) pairs into bucket-sorted order ----------
__global__ __launch_bounds__(256) void bscatter_kernel(const int* __restrict__ src,
                                                       const int* __restrict__ dst,
                                                       int* __restrict__ bcur,
                                                       int2* __restrict__ pairs, int E) {
    __shared__ int2 stage[CCH];     // 32 KB
    __shared__ int cnt[NBK];
    __shared__ int base[NBK];
    const int e0 = blockIdx.x * CCH;
    const int n  = min(CCH, E - e0);
    if (n <= 0) return;
    for (int i = threadIdx.x; i < NBK; i += 256) cnt[i] = 0;
    __syncthreads();
    for (int i = threadIdx.x; i < n; i += 256) {
        int2 p = make_int2(src[e0 + i], dst[e0 + i]);
        stage[i] = p;
        atomicAdd(&cnt[p.y >> BSH], 1);
    }
    __syncthreads();
    for (int i = threadIdx.x; i < NBK; i += 256) {
        int c = cnt[i];
        base[i] = c ? atomicAdd(&bcur[i], c) : 0;
        cnt[i] = 0;                 // reuse as local cursor
    }
    __syncthreads();
    for (int i = threadIdx.x; i < n; i += 256) {
        int2 p = stage[i];
        int b = p.y >> BSH;
        int pos = base[b] + atomicAdd(&cnt[b], 1);
        pairs[pos] = p;
    }
}

// ---------------- per-bucket CSR build: rowptr, dis, csr_src ----------------
__global__ __launch_bounds__(256) void csr_kernel(const int2* __restrict__ pairs,
                                                  const int* __restrict__ bbase,
                                                  int* __restrict__ rowptr,
                                                  int* __restrict__ csr_src,
                                                  float* __restrict__ dis,
                                                  int N, int E) {
    __shared__ int hist[BNODES];
    __shared__ int cur[BNODES];
    __shared__ int s[256];
    const int b     = blockIdx.x;
    const int t     = threadIdx.x;
    const int node0 = b << BSH;
    const int nn    = min(BNODES, N - node0);
    const int p0 = bbase[b], p1 = bbase[b + 1];

    for (int i = t; i < BNODES; i += 256) hist[i] = 0;
    __syncthreads();
    for (int i = p0 + t; i < p1; i += 256)
        atomicAdd(&hist[pairs[i].y - node0], 1);
    __syncthreads();

    int h0 = hist[2 * t], h1 = hist[2 * t + 1];
    int v = h0 + h1;
    s[t] = v;
    __syncthreads();
    for (int off = 1; off < 256; off <<= 1) {
        int u = (t >= off) ? s[t - off] : 0;
        __syncthreads();
        s[t] += u;
        __syncthreads();
    }
    int excl = s[t] - v;
    int e0 = p0 + excl;
    int e1 = e0 + h0;
    if (2 * t < nn) {
        rowptr[node0 + 2 * t] = e0;
        dis[node0 + 2 * t] = rsqrtf((float)h0 + 1.0f);
        cur[2 * t] = e0;
    }
    if (2 * t + 1 < nn) {
        rowptr[node0 + 2 * t + 1] = e1;
        dis[node0 + 2 * t + 1] = rsqrtf((float)h1 + 1.0f);
        cur[2 * t + 1] = e1;
    }
    if (b == NBK - 1 && t == 0) rowptr[N] = E;
    __syncthreads();

    for (int i = p0 + t; i < p1; i += 256) {
        int2 p = pairs[i];
        int pos = atomicAdd(&cur[p.y - node0], 1);
        csr_src[pos] = p.x;
    }
}

// ---------------- x16 prep: x16[i,k] = x[i,k]*dis[i] (k<15), 0 pad ---------
__global__ __launch_bounds__(256) void xprep_kernel(const float* __restrict__ x,
                                                    const float* __restrict__ dis,
                                                    float* __restrict__ x16, int N) {
    int gid = blockIdx.x * 256 + threadIdx.x;
    if (gid >= N * 16) return;
    int node = gid >> 4, k = gid & 15;
    x16[gid] = (k < 15) ? x[node * 15 + k] * dis[node] : 0.0f;
}

// ---------------- gather16: aggx = P*x  (quarter-wave per node) ------------
__global__ __launch_bounds__(256) void gather16_kernel(const float* __restrict__ x16,
                                                       const int* __restrict__ csr_src,
                                                       const int* __restrict__ rowptr,
                                                       const float* __restrict__ dis,
                                                       float* __restrict__ aggx, int N) {
    const int gid  = blockIdx.x * 256 + threadIdx.x;
    const int node = gid >> 4;
    if (node >= N) return;
    const int l  = threadIdx.x & 15;
    const int qb = threadIdx.x & 48;
    const int start = rowptr[node], end = rowptr[node + 1];
    const float* tl = x16 + l;
    float acc = 0.0f;
    for (int j0 = start; j0 < end; j0 += 16) {
        int j   = j0 + l;
        int s   = (j < end) ? csr_src[j] : 0;
        int cnt = min(16, end - j0);
        int k = 0;
        for (; k + 4 <= cnt; k += 4) {
            int s0 = __shfl(s, qb + k);
            int s1 = __shfl(s, qb + k + 1);
            int s2 = __shfl(s, qb + k + 2);
            int s3 = __shfl(s, qb + k + 3);
            float v0 = tl[s0 * 16];
            float v1 = tl[s1 * 16];
            float v2 = tl[s2 * 16];
            float v3 = tl[s3 * 16];
            acc += v0; acc += v1; acc += v2; acc += v3;
        }
        for (; k < cnt; ++k) acc += tl[__shfl(s, qb + k) * 16];
    }
    float sn = dis[node];
    aggx[(size_t)node * 16 + l] = sn * (acc + tl[node * 16]);
}

// ---------------- gemm1: h1pre = aggx @ W1  (fp32 out, no bias/relu/scale) --
// w1 is 15x64; rows 15.. of w_s zeroed (aggx col 15 is pad)
__global__ __launch_bounds__(256) void gemm1_kernel(const float* __restrict__ in,
                                                    const float* __restrict__ w,
                                                    float* __restrict__ h1pre, int N) {
    __shared__ float w_s[16 * 64];
    __shared__ float in_s[64 * 17];
    const int tid  = threadIdx.x;
    const int row0 = blockIdx.x * 64;
    const int rows = min(64, N - row0);

    for (int i = tid; i < 16 * 64; i += 256) w_s[i] = (i < 15 * 64) ? w[i] : 0.0f;
    for (int i = tid; i < rows * 16; i += 256) {
        int r = i >> 4, k = i & 15;
        in_s[r * 17 + k] = in[(size_t)(row0 + r) * 16 + k];
    }
    __syncthreads();

    const int r  = tid & 63;
    const int cg = tid >> 6;
    float acc[16];
#pragma unroll
    for (int i = 0; i < 16; ++i) acc[i] = 0.0f;
#pragma unroll
    for (int k = 0; k < 16; ++k) {
        float a = in_s[r * 17 + k];
#pragma unroll
        for (int cc = 0; cc < 16; ++cc)
            acc[cc] += a * w_s[k * 64 + cg * 16 + cc];
    }
    const int row = row0 + r;
    if (row < N) {
        float* hp = h1pre + (size_t)row * HID + cg * 16;
#pragma unroll
        for (int v4 = 0; v4 < 4; ++v4)
            reinterpret_cast<float4*>(hp)[v4] =
                make_float4(acc[4 * v4], acc[4 * v4 + 1],
                            acc[4 * v4 + 2], acc[4 * v4 + 3]);
    }
}

// ---------------- gemmB: th = fp16( relu(in+bias) @ w * dis ) ---------------
__global__ __launch_bounds__(256) void gemmB_kernel(const float* __restrict__ in,
                                                    const float* __restrict__ w,
                                                    const float* __restrict__ bias,
                                                    const float* __restrict__ dis,
                                                    __half* __restrict__ t, int N) {
    __shared__ float w_s[64 * 64];
    __shared__ float in_s[64 * 65];
    const int tid  = threadIdx.x;
    const int row0 = blockIdx.x * 64;
    const int rows = min(64, N - row0);

    for (int i = tid; i < 64 * 64; i += 256) w_s[i] = w[i];
    for (int i = tid; i < rows * 64; i += 256) {
        int r = i >> 6, k = i & 63;
        float v = in[(size_t)(row0 + r) * 64 + k];
        in_s[r * 65 + k] = fmaxf(v + bias[k], 0.0f);
    }
    __syncthreads();

    const int r  = tid & 63;
    const int cg = tid >> 6;
    float acc[16];
#pragma unroll
    for (int i = 0; i < 16; ++i) acc[i] = 0.0f;
#pragma unroll
    for (int k = 0; k < 64; ++k) {
        float a = in_s[r * 65 + k];
#pragma unroll
        for (int cc = 0; cc < 16; ++cc)
            acc[cc] += a * w_s[k * 64 + cg * 16 + cc];
    }
    const int row = row0 + r;
    if (row < N) {
        float sd = dis[row];
        __align__(16) __half2 hh[8];
#pragma unroll
        for (int i = 0; i < 8; ++i)
            hh[i] = __floats2half2_rn(acc[2 * i] * sd, acc[2 * i + 1] * sd);
        float4* tp = reinterpret_cast<float4*>(t + (size_t)row * HID + cg * 16);
        tp[0] = reinterpret_cast<float4*>(hh)[0];
        tp[1] = reinterpret_cast<float4*>(hh)[1];
    }
}

// ---------------- gather (fp16 table): half-wave per node ------------------
// agg[d,:] = dis[d] * (t[d,:] + sum t[src,:]) ; fp32 accumulate
__global__ __launch_bounds__(256) void gatherh_kernel(const __half2* __restrict__ th,
                                                      const int* __restrict__ csr_src,
                                                      const int* __restrict__ rowptr,
                                                      const float* __restrict__ dis,
                                                      float* __restrict__ agg, int N) {
    const int gid  = blockIdx.x * 256 + threadIdx.x;
    const int node = gid >> 5;
    if (node >= N) return;
    const int l  = threadIdx.x & 31;
    const int hb = threadIdx.x & 32;
    const int start = rowptr[node], end = rowptr[node + 1];
    const __half2* tl = th + l;
    float ax = 0.0f, ay = 0.0f;
    for (int j0 = start; j0 < end; j0 += 32) {
        int j   = j0 + l;
        int s   = (j < end) ? csr_src[j] : 0;
        int cnt = min(32, end - j0);
        int k = 0;
        for (; k + 8 <= cnt; k += 8) {
            int s0 = __shfl(s, hb + k);
            int s1 = __shfl(s, hb + k + 1);
            int s2 = __shfl(s, hb + k + 2);
            int s3 = __shfl(s, hb + k + 3);
            int s4 = __shfl(s, hb + k + 4);
            int s5 = __shfl(s, hb + k + 5);
            int s6 = __shfl(s, hb + k + 6);
            int s7 = __shfl(s, hb + k + 7);
            float2 v0 = __half22float2(tl[s0 * 32]);
            float2 v1 = __half22float2(tl[s1 * 32]);
            float2 v2 = __half22float2(tl[s2 * 32]);
            float2 v3 = __half22float2(tl[s3 * 32]);
            float2 v4 = __half22float2(tl[s4 * 32]);
            float2 v5 = __half22float2(tl[s5 * 32]);
            float2 v6 = __half22float2(tl[s6 * 32]);
            float2 v7 = __half22float2(tl[s7 * 32]);
            ax += v0.x; ay += v0.y; ax += v1.x; ay += v1.y;
            ax += v2.x; ay += v2.y; ax += v3.x; ay += v3.y;
            ax += v4.x; ay += v4.y; ax += v5.x; ay += v5.y;
            ax += v6.x; ay += v6.y; ax += v7.x; ay += v7.y;
        }
        for (; k < cnt; ++k) {
            float2 v = __half22float2(tl[__shfl(s, hb + k) * 32]);
            ax += v.x; ay += v.y;
        }
    }
    float sn = dis[node];
    float2 self = __half22float2(tl[node * 32]);
    ax = sn * (ax + self.x);
    ay = sn * (ay + self.y);
    reinterpret_cast<float2*>(agg)[(size_t)node * 32 + l] = make_float2(ax, ay);
}

// ---------------- mean pool (batch is sorted) ------------------------------
__global__ __launch_bounds__(256) void pool_kernel(const float* __restrict__ agg,
                                                   const float* __restrict__ b4,
                                                   const int* __restrict__ batch,
                                                   float* __restrict__ sums,
                                                   float* __restrict__ cnts, int N) {
    __shared__ float lsum[NG * HID];
    __shared__ float lcnt[NG];
    const int tid  = threadIdx.x;
    const int base = blockIdx.x * 256;
    const int last = min(base + 256, N) - 1;
    const int gfirst = batch[base];
    const int glast  = batch[last];
    const int span   = glast - gfirst + 1;

    for (int i = tid; i < span * HID; i += 256) lsum[i] = 0.0f;
    for (int i = tid; i < span; i += 256) lcnt[i] = 0.0f;
    __syncthreads();

    const int f = tid & 63, sub = tid >> 6;
    for (int n = base + sub; n < min(base + 256, N); n += 4) {
        int g = batch[n];
        float v = fmaxf(agg[(size_t)n * HID + f] + b4[f], 0.0f);
        atomicAdd(&lsum[(g - gfirst) * HID + f], v);
        if (f == 0) atomicAdd(&lcnt[g - gfirst], 1.0f);
    }
    __syncthreads();

    for (int i = tid; i < span * HID; i += 256)
        atomicAdd(&sums[(size_t)gfirst * HID + i], lsum[i]);
    for (int i = tid; i < span; i += 256) atomicAdd(&cnts[gfirst + i], lcnt[i]);
}

__global__ __launch_bounds__(256) void finalize_kernel(const float* __restrict__ sums,
                                                       const float* __restrict__ cnts,
                                                       float* __restrict__ out) {
    int i = blockIdx.x * 256 + threadIdx.x;
    if (i < NG * HID) out[i] = sums[i] / fmaxf(cnts[i >> 6], 1.0f);
}

// ---------------- launch ----------------
extern "C" void kernel_launch(void* const* d_in, const int* in_sizes, int n_in,
                              void* d_out, int out_size, void* d_ws, size_t ws_size,
                              hipStream_t stream) {
    const float* x  = (const float*)d_in[0];
    const float* w1 = (const float*)d_in[1];
    const float* b1 = (const float*)d_in[2];
    const float* w2 = (const float*)d_in[3];
    const float* b2 = (const float*)d_in[4];
    const float* w3 = (const float*)d_in[5];
    const float* b3 = (const float*)d_in[6];
    const float* w4 = (const float*)d_in[7];
    const float* b4 = (const float*)d_in[8];
    const int* ei    = (const int*)d_in[9];
    const int* batch = (const int*)d_in[10];
    const int* src = ei;
    const int* dst = ei + NE;

    // workspace layout:
    //   AGG (25.6 MB fp32) also serves as h1pre (dead before first gatherh)
    //   pairs (25.6 MB) dead after csr_kernel -> reused as x16|aggx|th
    float*  AGG     = (float*)d_ws;                        // NN*HID fp32
    float*  h1pre   = AGG;                                 // alias (see above)
    int2*   pairs   = (int2*)(AGG + (size_t)NN * HID);     // NE int2
    float*  x16     = (float*)pairs;                       // NN*16 fp32 (alias)
    float*  aggx    = x16 + (size_t)NN * 16;               // NN*16 fp32 (alias)
    __half* th      = (__half*)(aggx + (size_t)NN * 16);   // NN*HID fp16 (alias)
    int*    csr_src = (int*)(pairs + NE);                  // NE
    int*    rowptr  = csr_src + NE;                        // NN+1
    float*  dis     = (float*)(rowptr + NN + 1);           // NN
    int*    bcnt    = (int*)(dis + NN);                    // NBK
    int*    bbase   = bcnt + NBK;                          // NBK+1
    int*    bcur    = bbase + NBK + 1;                     // NBK
    float*  sums    = (float*)(bcur + NBK);                // NG*HID
    float*  cnts    = sums + NG * HID;                     // NG

    float* out = (float*)d_out;

    const int NB  = (NN + 255) / 256;
    const int GB  = (NN + 63) / 64;
    const int QB  = (NN * 16 + 255) / 256;   // quarter-wave gather / xprep
    const int HB  = (NN * 32 + 255) / 256;   // half-wave gather
    const int CB  = (NE + CCH - 1) / CCH;

    hipMemsetAsync(bcnt, 0, NBK * sizeof(int), stream);
    hipMemsetAsync(sums, 0, (NG * HID + NG) * sizeof(float), stream);

    bcount_kernel<<<512, 256, 0, stream>>>(dst, bcnt, NE);
    bscan_kernel<<<1, 256, 0, stream>>>(bcnt, bbase, bcur, NE);
    bscatter_kernel<<<CB, 256, 0, stream>>>(src, dst, bcur, pairs, NE);
    csr_kernel<<<NBK, 256, 0, stream>>>(pairs, bbase, rowptr, csr_src, dis, NN, NE);

    // layer 1 (commuted): aggx = P*x ; h1pre = aggx @ W1
    xprep_kernel<<<QB, 256, 0, stream>>>(x, dis, x16, NN);
    gather16_kernel<<<QB, 256, 0, stream>>>(x16, csr_src, rowptr, dis, aggx, NN);
    gemm1_kernel<<<GB, 256, 0, stream>>>(aggx, w1, h1pre, NN);
    // layer 2: th = relu(h1pre+b1)@W2*dis ; h2pre = P_hat * th
    gemmB_kernel<<<GB, 256, 0, stream>>>(h1pre, w2, b1, dis, th, NN);
    gatherh_kernel<<<HB, 256, 0, stream>>>((const __half2*)th, csr_src, rowptr, dis, AGG, NN);
    // layer 3
    gemmB_kernel<<<GB, 256, 0, stream>>>(AGG, w3, b2, dis, th, NN);
    gatherh_kernel<<<HB, 256, 0, stream>>>((const __half2*)th, csr_src, rowptr, dis, AGG, NN);
    // layer 4
    gemmB_kernel<<<GB, 256, 0, stream>>>(AGG, w4, b3, dis, th, NN);
    gatherh_kernel<<<HB, 256, 0, stream>>>((const __half2*)th, csr_src, rowptr, dis, AGG, NN);

    pool_kernel<<<NB, 256, 0, stream>>>(AGG, b4, batch, sums, cnts, NN);
    finalize_kernel<<<(NG * HID + 255) / 256, 256, 0, stream>>>(sums, cnts, out);
}

// Round 8
// 553.047 us; speedup vs baseline: 20.2197x; 1.0302x over previous
//
#include <hip/hip_runtime.h>
#include <hip/hip_fp16.h>

#define NN 100000
#define NE 3200000
#define NG 128
#define HID 64

#define BSH 9                       // nodes per bucket = 512
#define BNODES 512
#define NBK ((NN + BNODES - 1) / BNODES)   // 196
#define CCH 4096                    // edges staged per block in bscatter

typedef __attribute__((ext_vector_type(2))) _Float16 half2v;

#if __has_builtin(__builtin_amdgcn_fdot2)
#define HAVE_FDOT2 1
#else
#define HAVE_FDOT2 0
#endif

// ---------------- bucket count: hist of dst>>BSH ----------------
__global__ __launch_bounds__(256) void bcount_kernel(const int* __restrict__ dst,
                                                     int* __restrict__ bcnt, int E) {
    __shared__ int h[NBK];
    for (int i = threadIdx.x; i < NBK; i += 256) h[i] = 0;
    __syncthreads();
    for (int e = blockIdx.x * 256 + threadIdx.x; e < E; e += gridDim.x * 256)
        atomicAdd(&h[dst[e] >> BSH], 1);
    __syncthreads();
    for (int i = threadIdx.x; i < NBK; i += 256)
        if (h[i]) atomicAdd(&bcnt[i], h[i]);
}

// ---------------- bucket scan (196 values, 1 block) ----------------
__global__ __launch_bounds__(256) void bscan_kernel(const int* __restrict__ bcnt,
                                                    int* __restrict__ bbase,
                                                    int* __restrict__ bcur, int E) {
    __shared__ int s[NBK];
    int t = threadIdx.x;
    if (t < NBK) s[t] = bcnt[t];
    __syncthreads();
    if (t == 0) {
        int acc = 0;
        for (int i = 0; i < NBK; ++i) { int v = s[i]; s[i] = acc; acc += v; }
    }
    __syncthreads();
    if (t < NBK) { bbase[t] = s[t]; bcur[t] = s[t]; }
    if (t == 0) bbase[NBK] = E;
}

// ---------------- scatter packed (dstLocal<<17 | src) into bucket order -----
__global__ __launch_bounds__(256) void bscatter_kernel(const int* __restrict__ src,
                                                       const int* __restrict__ dst,
                                                       int* __restrict__ bcur,
                                                       unsigned* __restrict__ pairs,
                                                       int E) {
    __shared__ unsigned stage[CCH];      // 16 KB
    __shared__ unsigned char bb[CCH];    // 4 KB
    __shared__ int cnt[NBK];
    __shared__ int base[NBK];
    const int e0 = blockIdx.x * CCH;
    const int n  = min(CCH, E - e0);
    if (n <= 0) return;
    for (int i = threadIdx.x; i < NBK; i += 256) cnt[i] = 0;
    __syncthreads();
    for (int i = threadIdx.x; i < n; i += 256) {
        int s = src[e0 + i], d = dst[e0 + i];
        int b = d >> BSH;
        stage[i] = ((unsigned)(d & (BNODES - 1)) << 17) | (unsigned)s;
        bb[i] = (unsigned char)b;
        atomicAdd(&cnt[b], 1);
    }
    __syncthreads();
    for (int i = threadIdx.x; i < NBK; i += 256) {
        int c = cnt[i];
        base[i] = c ? atomicAdd(&bcur[i], c) : 0;
        cnt[i] = 0;                 // reuse as local cursor
    }
    __syncthreads();
    for (int i = threadIdx.x; i < n; i += 256) {
        int b = bb[i];
        int pos = base[b] + atomicAdd(&cnt[b], 1);
        pairs[pos] = stage[i];
    }
}

// ---------------- per-bucket CSR build: rowptr, dis, csr_src ----------------
__global__ __launch_bounds__(256) void csr_kernel(const unsigned* __restrict__ pairs,
                                                  const int* __restrict__ bbase,
                                                  int* __restrict__ rowptr,
                                                  int* __restrict__ csr_src,
                                                  float* __restrict__ dis,
                                                  int N, int E) {
    __shared__ int hist[BNODES];
    __shared__ int cur[BNODES];
    __shared__ int s[256];
    const int b     = blockIdx.x;
    const int t     = threadIdx.x;
    const int node0 = b << BSH;
    const int nn    = min(BNODES, N - node0);
    const int p0 = bbase[b], p1 = bbase[b + 1];

    for (int i = t; i < BNODES; i += 256) hist[i] = 0;
    __syncthreads();
    for (int i = p0 + t; i < p1; i += 256)
        atomicAdd(&hist[pairs[i] >> 17], 1);
    __syncthreads();

    int h0 = hist[2 * t], h1 = hist[2 * t + 1];
    int v = h0 + h1;
    s[t] = v;
    __syncthreads();
    for (int off = 1; off < 256; off <<= 1) {
        int u = (t >= off) ? s[t - off] : 0;
        __syncthreads();
        s[t] += u;
        __syncthreads();
    }
    int excl = s[t] - v;
    int e0 = p0 + excl;
    int e1 = e0 + h0;
    if (2 * t < nn) {
        rowptr[node0 + 2 * t] = e0;
        dis[node0 + 2 * t] = rsqrtf((float)h0 + 1.0f);
        cur[2 * t] = e0;
    }
    if (2 * t + 1 < nn) {
        rowptr[node0 + 2 * t + 1] = e1;
        dis[node0 + 2 * t + 1] = rsqrtf((float)h1 + 1.0f);
        cur[2 * t + 1] = e1;
    }
    if (b == NBK - 1 && t == 0) rowptr[N] = E;
    __syncthreads();

    for (int i = p0 + t; i < p1; i += 256) {
        unsigned p = pairs[i];
        int pos = atomicAdd(&cur[p >> 17], 1);
        csr_src[pos] = (int)(p & 0x1FFFFu);
    }
}

// ---------------- x16h prep: fp16( x[i,k]*dis[i] ), 0 pad -------------------
__global__ __launch_bounds__(256) void xprep_kernel(const float* __restrict__ x,
                                                    const float* __restrict__ dis,
                                                    __half* __restrict__ x16h, int N) {
    int gid = blockIdx.x * 256 + threadIdx.x;
    if (gid >= N * 16) return;
    int node = gid >> 4, k = gid & 15;
    float v = (k < 15) ? x[node * 15 + k] * dis[node] : 0.0f;
    x16h[gid] = __float2half(v);
}

// ---------------- gather16: aggx = P_hat * (x*dis)  (8 lanes per node) ------
__global__ __launch_bounds__(256) void gather16_kernel(const half2v* __restrict__ xh,
                                                       const int* __restrict__ csr_src,
                                                       const int* __restrict__ rowptr,
                                                       const float* __restrict__ dis,
                                                       float* __restrict__ aggx, int N) {
    const int gid  = blockIdx.x * 256 + threadIdx.x;
    const int node = gid >> 3;
    if (node >= N) return;
    const int l  = threadIdx.x & 7;
    const int ob = threadIdx.x & 56;
    const int start = rowptr[node], end = rowptr[node + 1];
    const half2v* tl = xh + l;
    const half2v ONEX = {(_Float16)1.0f, (_Float16)0.0f};
    const half2v ONEY = {(_Float16)0.0f, (_Float16)1.0f};
    float ax = 0.0f, ay = 0.0f;
    for (int j0 = start; j0 < end; j0 += 8) {
        int j   = j0 + l;
        int s   = (j < end) ? csr_src[j] : 0;
        int cnt = min(8, end - j0);
        int k = 0;
        for (; k + 4 <= cnt; k += 4) {
            int s0 = __shfl(s, ob + k);
            int s1 = __shfl(s, ob + k + 1);
            int s2 = __shfl(s, ob + k + 2);
            int s3 = __shfl(s, ob + k + 3);
            half2v v0 = tl[s0 * 8];
            half2v v1 = tl[s1 * 8];
            half2v v2 = tl[s2 * 8];
            half2v v3 = tl[s3 * 8];
#if HAVE_FDOT2
            ax = __builtin_amdgcn_fdot2(v0, ONEX, ax, false);
            ay = __builtin_amdgcn_fdot2(v0, ONEY, ay, false);
            ax = __builtin_amdgcn_fdot2(v1, ONEX, ax, false);
            ay = __builtin_amdgcn_fdot2(v1, ONEY, ay, false);
            ax = __builtin_amdgcn_fdot2(v2, ONEX, ax, false);
            ay = __builtin_amdgcn_fdot2(v2, ONEY, ay, false);
            ax = __builtin_amdgcn_fdot2(v3, ONEX, ax, false);
            ay = __builtin_amdgcn_fdot2(v3, ONEY, ay, false);
#else
            ax += (float)v0.x; ay += (float)v0.y;
            ax += (float)v1.x; ay += (float)v1.y;
            ax += (float)v2.x; ay += (float)v2.y;
            ax += (float)v3.x; ay += (float)v3.y;
#endif
        }
        for (; k < cnt; ++k) {
            half2v v = tl[__shfl(s, ob + k) * 8];
            ax += (float)v.x; ay += (float)v.y;
        }
    }
    half2v self = tl[node * 8];
    ax += (float)self.x; ay += (float)self.y;
    float sn = dis[node];
    reinterpret_cast<float2*>(aggx)[(size_t)node * 8 + l] =
        make_float2(sn * ax, sn * ay);
}

// ---------------- gemm1: h1pre = aggx @ W1  (fp32 out) ----------------------
__global__ __launch_bounds__(256) void gemm1_kernel(const float* __restrict__ in,
                                                    const float* __restrict__ w,
                                                    float* __restrict__ h1pre, int N) {
    __shared__ float w_s[16 * 64];
    __shared__ float in_s[64 * 17];
    const int tid  = threadIdx.x;
    const int row0 = blockIdx.x * 64;
    const int rows = min(64, N - row0);

    for (int i = tid; i < 16 * 64; i += 256) w_s[i] = (i < 15 * 64) ? w[i] : 0.0f;
    for (int i = tid; i < rows * 16; i += 256) {
        int r = i >> 4, k = i & 15;
        in_s[r * 17 + k] = in[(size_t)(row0 + r) * 16 + k];
    }
    __syncthreads();

    const int r  = tid & 63;
    const int cg = tid >> 6;
    float acc[16];
#pragma unroll
    for (int i = 0; i < 16; ++i) acc[i] = 0.0f;
#pragma unroll
    for (int k = 0; k < 16; ++k) {
        float a = in_s[r * 17 + k];
#pragma unroll
        for (int cc = 0; cc < 16; ++cc)
            acc[cc] += a * w_s[k * 64 + cg * 16 + cc];
    }
    const int row = row0 + r;
    if (row < N) {
        float* hp = h1pre + (size_t)row * HID + cg * 16;
#pragma unroll
        for (int v4 = 0; v4 < 4; ++v4)
            reinterpret_cast<float4*>(hp)[v4] =
                make_float4(acc[4 * v4], acc[4 * v4 + 1],
                            acc[4 * v4 + 2], acc[4 * v4 + 3]);
    }
}

// ---------------- gemmB: th = fp16( relu(in+bias) @ w * dis ) ---------------
__global__ __launch_bounds__(256) void gemmB_kernel(const float* __restrict__ in,
                                                    const float* __restrict__ w,
                                                    const float* __restrict__ bias,
                                                    const float* __restrict__ dis,
                                                    __half* __restrict__ t, int N) {
    __shared__ float w_s[64 * 64];
    __shared__ float in_s[64 * 65];
    const int tid  = threadIdx.x;
    const int row0 = blockIdx.x * 64;
    const int rows = min(64, N - row0);

    for (int i = tid; i < 64 * 64; i += 256) w_s[i] = w[i];
    for (int i = tid; i < rows * 64; i += 256) {
        int r = i >> 6, k = i & 63;
        float v = in[(size_t)(row0 + r) * 64 + k];
        in_s[r * 65 + k] = fmaxf(v + bias[k], 0.0f);
    }
    __syncthreads();

    const int r  = tid & 63;
    const int cg = tid >> 6;
    float acc[16];
#pragma unroll
    for (int i = 0; i < 16; ++i) acc[i] = 0.0f;
#pragma unroll
    for (int k = 0; k < 64; ++k) {
        float a = in_s[r * 65 + k];
#pragma unroll
        for (int cc = 0; cc < 16; ++cc)
            acc[cc] += a * w_s[k * 64 + cg * 16 + cc];
    }
    const int row = row0 + r;
    if (row < N) {
        float sd = dis[row];
        __align__(16) __half2 hh[8];
#pragma unroll
        for (int i = 0; i < 8; ++i)
            hh[i] = __floats2half2_rn(acc[2 * i] * sd, acc[2 * i + 1] * sd);
        float4* tp = reinterpret_cast<float4*>(t + (size_t)row * HID + cg * 16);
        tp[0] = reinterpret_cast<float4*>(hh)[0];
        tp[1] = reinterpret_cast<float4*>(hh)[1];
    }
}

// ---------------- gatherh (fp16 table): half-wave per node ------------------
// agg[d,:] = dis[d] * (t[d,:] + sum t[src,:]) ; exact fp32 accumulate (fdot2)
__global__ __launch_bounds__(256) void gatherh_kernel(const half2v* __restrict__ th,
                                                      const int* __restrict__ csr_src,
                                                      const int* __restrict__ rowptr,
                                                      const float* __restrict__ dis,
                                                      float* __restrict__ agg, int N) {
    const int gid  = blockIdx.x * 256 + threadIdx.x;
    const int node = gid >> 5;
    if (node >= N) return;
    const int l  = threadIdx.x & 31;
    const int hb = threadIdx.x & 32;
    const int start = rowptr[node], end = rowptr[node + 1];
    const half2v* tl = th + l;
    const half2v ONEX = {(_Float16)1.0f, (_Float16)0.0f};
    const half2v ONEY = {(_Float16)0.0f, (_Float16)1.0f};
    float ax = 0.0f, ay = 0.0f;
    for (int j0 = start; j0 < end; j0 += 32) {
        int j   = j0 + l;
        int s   = (j < end) ? csr_src[j] : 0;
        int cnt = min(32, end - j0);
        int k = 0;
        for (; k + 8 <= cnt; k += 8) {
            int s0 = __shfl(s, hb + k);
            int s1 = __shfl(s, hb + k + 1);
            int s2 = __shfl(s, hb + k + 2);
            int s3 = __shfl(s, hb + k + 3);
            int s4 = __shfl(s, hb + k + 4);
            int s5 = __shfl(s, hb + k + 5);
            int s6 = __shfl(s, hb + k + 6);
            int s7 = __shfl(s, hb + k + 7);
            half2v v0 = tl[s0 * 32];
            half2v v1 = tl[s1 * 32];
            half2v v2 = tl[s2 * 32];
            half2v v3 = tl[s3 * 32];
            half2v v4 = tl[s4 * 32];
            half2v v5 = tl[s5 * 32];
            half2v v6 = tl[s6 * 32];
            half2v v7 = tl[s7 * 32];
#if HAVE_FDOT2
            ax = __builtin_amdgcn_fdot2(v0, ONEX, ax, false);
            ay = __builtin_amdgcn_fdot2(v0, ONEY, ay, false);
            ax = __builtin_amdgcn_fdot2(v1, ONEX, ax, false);
            ay = __builtin_amdgcn_fdot2(v1, ONEY, ay, false);
            ax = __builtin_amdgcn_fdot2(v2, ONEX, ax, false);
            ay = __builtin_amdgcn_fdot2(v2, ONEY, ay, false);
            ax = __builtin_amdgcn_fdot2(v3, ONEX, ax, false);
            ay = __builtin_amdgcn_fdot2(v3, ONEY, ay, false);
            ax = __builtin_amdgcn_fdot2(v4, ONEX, ax, false);
            ay = __builtin_amdgcn_fdot2(v4, ONEY, ay, false);
            ax = __builtin_amdgcn_fdot2(v5, ONEX, ax, false);
            ay = __builtin_amdgcn_fdot2(v5, ONEY, ay, false);
            ax = __builtin_amdgcn_fdot2(v6, ONEX, ax, false);
            ay = __builtin_amdgcn_fdot2(v6, ONEY, ay, false);
            ax = __builtin_amdgcn_fdot2(v7, ONEX, ax, false);
            ay = __builtin_amdgcn_fdot2(v7, ONEY, ay, false);
#else
            ax += (float)v0.x; ay += (float)v0.y;
            ax += (float)v1.x; ay += (float)v1.y;
            ax += (float)v2.x; ay += (float)v2.y;
            ax += (float)v3.x; ay += (float)v3.y;
            ax += (float)v4.x; ay += (float)v4.y;
            ax += (float)v5.x; ay += (float)v5.y;
            ax += (float)v6.x; ay += (float)v6.y;
            ax += (float)v7.x; ay += (float)v7.y;
#endif
        }
        for (; k < cnt; ++k) {
            half2v v = tl[__shfl(s, hb + k) * 32];
            ax += (float)v.x; ay += (float)v.y;
        }
    }
    half2v self = tl[node * 32];
    ax += (float)self.x; ay += (float)self.y;
    float sn = dis[node];
    reinterpret_cast<float2*>(agg)[(size_t)node * 32 + l] =
        make_float2(sn * ax, sn * ay);
}

// ---------------- mean pool (batch is sorted) ------------------------------
__global__ __launch_bounds__(256) void pool_kernel(const float* __restrict__ agg,
                                                   const float* __restrict__ b4,
                                                   const int* __restrict__ batch,
                                                   float* __restrict__ sums,
                                                   float* __restrict__ cnts, int N) {
    __shared__ float lsum[NG * HID];
    __shared__ float lcnt[NG];
    const int tid  = threadIdx.x;
    const int base = blockIdx.x * 256;
    const int last = min(base + 256, N) - 1;
    const int gfirst = batch[base];
    const int glast  = batch[last];
    const int span   = glast - gfirst + 1;

    for (int i = tid; i < span * HID; i += 256) lsum[i] = 0.0f;
    for (int i = tid; i < span; i += 256) lcnt[i] = 0.0f;
    __syncthreads();

    const int f = tid & 63, sub = tid >> 6;
    for (int n = base + sub; n < min(base + 256, N); n += 4) {
        int g = batch[n];
        float v = fmaxf(agg[(size_t)n * HID + f] + b4[f], 0.0f);
        atomicAdd(&lsum[(g - gfirst) * HID + f], v);
        if (f == 0) atomicAdd(&lcnt[g - gfirst], 1.0f);
    }
    __syncthreads();

    for (int i = tid; i < span * HID; i += 256)
        atomicAdd(&sums[(size_t)gfirst * HID + i], lsum[i]);
    for (int i = tid; i < span; i += 256) atomicAdd(&cnts[gfirst + i], lcnt[i]);
}

__global__ __launch_bounds__(256) void finalize_kernel(const float* __restrict__ sums,
                                                       const float* __restrict__ cnts,
                                                       float* __restrict__ out) {
    int i = blockIdx.x * 256 + threadIdx.x;
    if (i < NG * HID) out[i] = sums[i] / fmaxf(cnts[i >> 6], 1.0f);
}

// ---------------- launch ----------------
extern "C" void kernel_launch(void* const* d_in, const int* in_sizes, int n_in,
                              void* d_out, int out_size, void* d_ws, size_t ws_size,
                              hipStream_t stream) {
    const float* x  = (const float*)d_in[0];
    const float* w1 = (const float*)d_in[1];
    const float* b1 = (const float*)d_in[2];
    const float* w2 = (const float*)d_in[3];
    const float* b2 = (const float*)d_in[4];
    const float* w3 = (const float*)d_in[5];
    const float* b3 = (const float*)d_in[6];
    const float* w4 = (const float*)d_in[7];
    const float* b4 = (const float*)d_in[8];
    const int* ei    = (const int*)d_in[9];
    const int* batch = (const int*)d_in[10];
    const int* src = ei;
    const int* dst = ei + NE;

    // workspace layout:
    //   AGG (25.6 MB fp32) also serves as h1pre
    //   region (22.4 MB): pairs (12.8, dead after csr) overlaps x16h|aggx|th
    float*    AGG     = (float*)d_ws;                        // NN*HID fp32
    float*    h1pre   = AGG;
    unsigned* pairs   = (unsigned*)(AGG + (size_t)NN * HID); // NE uint (12.8 MB)
    __half*   x16h    = (__half*)pairs;                      // NN*16 fp16 (3.2 MB)
    float*    aggx    = (float*)(x16h + (size_t)NN * 16);    // NN*16 fp32 (6.4 MB)
    __half*   th      = (__half*)(aggx + (size_t)NN * 16);   // NN*HID fp16 (12.8 MB)
    int*      csr_src = (int*)(th + (size_t)NN * HID);       // NE
    int*      rowptr  = csr_src + NE;                        // NN+1
    float*    dis     = (float*)(rowptr + NN + 1);           // NN
    int*      bcnt    = (int*)(dis + NN);                    // NBK
    int*      bbase   = bcnt + NBK;                          // NBK+1
    int*      bcur    = bbase + NBK + 1;                     // NBK
    float*    sums    = (float*)(bcur + NBK);                // NG*HID
    float*    cnts    = sums + NG * HID;                     // NG

    float* out = (float*)d_out;

    const int NB  = (NN + 255) / 256;
    const int GB  = (NN + 63) / 64;
    const int XB  = (NN * 16 + 255) / 256;   // xprep
    const int OB  = (NN * 8 + 255) / 256;    // gather16: 8 lanes/node
    const int HB  = (NN * 32 + 255) / 256;   // gatherh: 32 lanes/node
    const int CB  = (NE + CCH - 1) / CCH;

    hipMemsetAsync(bcnt, 0, NBK * sizeof(int), stream);
    hipMemsetAsync(sums, 0, (NG * HID + NG) * sizeof(float), stream);

    bcount_kernel<<<512, 256, 0, stream>>>(dst, bcnt, NE);
    bscan_kernel<<<1, 256, 0, stream>>>(bcnt, bbase, bcur, NE);
    bscatter_kernel<<<CB, 256, 0, stream>>>(src, dst, bcur, pairs, NE);
    csr_kernel<<<NBK, 256, 0, stream>>>(pairs, bbase, rowptr, csr_src, dis, NN, NE);

    // layer 1 (commuted): aggx = P_hat*(x*dis row-scaled) ; h1pre = aggx @ W1
    xprep_kernel<<<XB, 256, 0, stream>>>(x, dis, x16h, NN);
    gather16_kernel<<<OB, 256, 0, stream>>>((const half2v*)x16h, csr_src, rowptr, dis, aggx, NN);
    gemm1_kernel<<<GB, 256, 0, stream>>>(aggx, w1, h1pre, NN);
    // layers 2..4
    gemmB_kernel<<<GB, 256, 0, stream>>>(h1pre, w2, b1, dis, th, NN);
    gatherh_kernel<<<HB, 256, 0, stream>>>((const half2v*)th, csr_src, rowptr, dis, AGG, NN);
    gemmB_kernel<<<GB, 256, 0, stream>>>(AGG, w3, b2, dis, th, NN);
    gatherh_kernel<<<HB, 256, 0, stream>>>((const half2v*)th, csr_src, rowptr, dis, AGG, NN);
    gemmB_kernel<<<GB, 256, 0, stream>>>(AGG, w4, b3, dis, th, NN);
    gatherh_kernel<<<HB, 256, 0, stream>>>((const half2v*)th, csr_src, rowptr, dis, AGG, NN);

    pool_kernel<<<NB, 256, 0, stream>>>(AGG, b4, batch, sums, cnts, NN);
    finalize_kernel<<<(NG * HID + 255) / 256, 256, 0, stream>>>(sums, cnts, out);
}